// Round 11
// baseline (337.365 us; speedup 1.0000x reference)
//
#include <hip/hip_runtime.h>
#include <hip/hip_bf16.h>

typedef unsigned short u16;
typedef __bf16 bf16x8_t __attribute__((ext_vector_type(8)));
typedef float f32x4_t __attribute__((ext_vector_type(4)));

struct alignas(8) us4 { u16 v[4]; };

__device__ __forceinline__ u16 f2bf(float f) {
  __hip_bfloat16 h = __float2bfloat16(f);
  u16 u; __builtin_memcpy(&u, &h, 2); return u;
}

__device__ __forceinline__ void gload16(const u16* g, u16* l) {
  __builtin_amdgcn_global_load_lds(
      (const __attribute__((address_space(1))) void*)g,
      (__attribute__((address_space(3))) void*)l, 16, 0, 0);
}

#define BAR()  __builtin_amdgcn_s_barrier()
#define LGKM0() do { asm volatile("s_waitcnt lgkmcnt(0)" ::: "memory"); \
                     __builtin_amdgcn_sched_barrier(0); } while (0)
#define VMC(n) asm volatile("s_waitcnt vmcnt(%0)" :: "i"(n) : "memory")

// ================= 8-phase 256x256 projection kernel =================
// C[m][n] = sum_k A[m][k]*B[n][k]; A [8192][512] bf16, B pre-interleaved
// [4096][512] bf16 (row n -> h=(n>>4)&7, e=(n>>7)*16+(n&15)). K=512, BK=64.
// 8 waves (512 thr): wm=(wave>>2)*128, wn=(wave&3)*64; acc 8x4 frags.
// LDS 128 KiB: 2 K-tile buffers x (A 256x64 + B 256x64), chunk-XOR swizzled.
// Schedule per iteration (2 K-tiles): reads front-loaded (P0/P1, P4/P5 = 12
// ds_read_b128 each), 1 half-tile staged per phase, vmcnt(4) at end-P3/P7,
// setprio around MFMA clusters. MODE 0 -> qsP (identity cols); MODE 1 ->
// [b,h,e,s] via 4-slab LDS transpose. SM fuses softmax-over-heads.
template<int MODE, bool SM>
__global__ __launch_bounds__(512, 2)
void proj8_kernel(const u16* __restrict__ A, const u16* __restrict__ B,
                  const float* __restrict__ bias, u16* __restrict__ out)
{
  __shared__ __align__(16) u16 smem[65536];  // 131072 B

  const int bid = blockIdx.x;               // grid 512 = 16 bx * 32 by
  const int wg = (bid & 7) * 64 + (bid >> 3);
  const int by = wg >> 4;
  const int bx = wg & 15;
  const int m0 = by * 256, n0 = bx * 256;

  const int tid = threadIdx.x;
  const int lane = tid & 63;
  const int wave = tid >> 6;
  const int wm = (wave >> 2) * 128;
  const int wn = (wave & 3) * 64;
  const int fr = lane & 15;
  const int kg16 = lane >> 4;

  // staging: thread stages chunks (row r0c, r0c+64) at swizzled k-chunk gk
  const int r0c = tid >> 3;
  const int gk = (tid & 7) ^ (r0c & 7);
  const u16* Ar0 = A + (long)(m0 + r0c) * 512 + gk * 8;
  const u16* Br0 = B + (long)(n0 + r0c) * 512 + gk * 8;

  auto ST = [&](int T, int part) {   // part: 0=A0,1=A1,2=B0,3=B1
    u16* d = smem + ((T & 1) << 15) + (part << 13) + tid * 8;
    const u16* s = (part < 2 ? Ar0 : Br0) + ((part & 1) ? 65536 : 0) + T * 64;
    gload16(s, d);
    gload16(s + 32768, d + 4096);
  };

  // fragment read offsets (u16, within buffer): A row r=rA+i*16, B row rB+j*16
  const int rA = wm + fr, rB = wn + fr;
  const int offA0 = rA * 64 + (((0 + kg16) ^ (rA & 7)) << 3);  // ks0
  const int offA1 = rA * 64 + (((4 + kg16) ^ (rA & 7)) << 3);  // ks1
  const int offB0 = 16384 + rB * 64 + (((0 + kg16) ^ (rB & 7)) << 3);
  const int offB1 = 16384 + rB * 64 + (((4 + kg16) ^ (rB & 7)) << 3);

  f32x4_t acc[8][4];
#pragma unroll
  for (int i = 0; i < 8; i++)
#pragma unroll
    for (int j = 0; j < 4; j++) acc[i][j] = (f32x4_t){0.f, 0.f, 0.f, 0.f};

  bf16x8_t a0[4], a1[4], a2[4], a3[4], b0v[4], b1v[4];

#define RD_P0(cb) do { \
  _Pragma("unroll") for (int i = 0; i < 4; i++) a0[i] = *(const bf16x8_t*)&cb[offA0 + i * 1024]; \
  _Pragma("unroll") for (int j = 0; j < 4; j++) b0v[j] = *(const bf16x8_t*)&cb[offB0 + j * 1024]; \
  _Pragma("unroll") for (int j = 0; j < 4; j++) b1v[j] = *(const bf16x8_t*)&cb[offB1 + j * 1024]; \
} while (0)
#define RD_P1(cb) do { \
  _Pragma("unroll") for (int i = 0; i < 4; i++) a1[i] = *(const bf16x8_t*)&cb[offA0 + (i + 4) * 1024]; \
  _Pragma("unroll") for (int i = 0; i < 4; i++) a2[i] = *(const bf16x8_t*)&cb[offA1 + i * 1024]; \
  _Pragma("unroll") for (int i = 0; i < 4; i++) a3[i] = *(const bf16x8_t*)&cb[offA1 + (i + 4) * 1024]; \
} while (0)
#define MMBLK(af, bf, ilo) do { \
  __builtin_amdgcn_s_setprio(1); \
  _Pragma("unroll") for (int i = 0; i < 4; i++) \
    _Pragma("unroll") for (int j = 0; j < 4; j++) \
      acc[i + ilo][j] = __builtin_amdgcn_mfma_f32_16x16x32_bf16(af[i], bf[j], acc[i + ilo][j], 0, 0, 0); \
  __builtin_amdgcn_s_setprio(0); \
} while (0)

  // prologue: T0 all 4 halves + T1 A halves; keep T1.A in flight (vmcnt(4))
  ST(0, 0); ST(0, 1); ST(0, 2); ST(0, 3); ST(1, 0); ST(1, 1);
  VMC(4);
  BAR();

  const u16* c0 = smem;
  const u16* c1 = smem + 32768;

  for (int m = 0; m < 3; m++) {          // main iters; K-tiles 2m, 2m+1
    const int T0 = 2 * m, T1 = 2 * m + 1;
    // P0
    RD_P0(c0); ST(T1, 2);
    BAR(); LGKM0(); MMBLK(a0, b0v, 0); BAR();
    // P1
    RD_P1(c0); ST(T1, 3);
    BAR(); LGKM0(); MMBLK(a1, b0v, 4); BAR();
    // P2
    ST(T0 + 2, 0);
    BAR(); __builtin_amdgcn_sched_barrier(0); MMBLK(a2, b1v, 0); BAR();
    // P3
    ST(T0 + 2, 1);
    BAR(); __builtin_amdgcn_sched_barrier(0); MMBLK(a3, b1v, 4); VMC(4); BAR();
    // P4
    RD_P0(c1); ST(T0 + 2, 2);
    BAR(); LGKM0(); MMBLK(a0, b0v, 0); BAR();
    // P5
    RD_P1(c1); ST(T0 + 2, 3);
    BAR(); LGKM0(); MMBLK(a1, b0v, 4); BAR();
    // P6
    ST(T0 + 3, 0);
    BAR(); __builtin_amdgcn_sched_barrier(0); MMBLK(a2, b1v, 0); BAR();
    // P7
    ST(T0 + 3, 1);
    BAR(); __builtin_amdgcn_sched_barrier(0); MMBLK(a3, b1v, 4); VMC(4); BAR();
    (void)T1;
  }
  {  // peeled last iteration: K-tiles 6 (buf0), 7 (buf1)
    RD_P0(c0); ST(7, 2);
    BAR(); LGKM0(); MMBLK(a0, b0v, 0); BAR();
    RD_P1(c0); ST(7, 3);
    BAR(); LGKM0(); MMBLK(a1, b0v, 4); BAR();
    BAR(); __builtin_amdgcn_sched_barrier(0); MMBLK(a2, b1v, 0); BAR();
    BAR(); __builtin_amdgcn_sched_barrier(0); MMBLK(a3, b1v, 4); VMC(0); BAR();
    RD_P0(c1);
    BAR(); LGKM0(); MMBLK(a0, b0v, 0); BAR();
    RD_P1(c1);
    BAR(); LGKM0(); MMBLK(a1, b0v, 4); BAR();
    BAR(); __builtin_amdgcn_sched_barrier(0); MMBLK(a2, b1v, 0); BAR();
    BAR(); __builtin_amdgcn_sched_barrier(0); MMBLK(a3, b1v, 4); BAR();
  }
  __syncthreads();

  // ---- fused softmax over heads ----
  const int hbase = ((wn >> 6) & 1) * 4;
  const int eb = (wn >> 7) & 1;
  const int e_ = bx * 32 + eb * 16 + fr;
  if constexpr (SM) {
    float* ex = (float*)smem;
    const int self = (wave * 64 + lane) * 33;
    const int part = ((wave ^ 1) * 64 + lane) * 33;
    float bj[4];
#pragma unroll
    for (int j = 0; j < 4; j++) bj[j] = bias[(hbase + j) * 512 + e_];
#pragma unroll
    for (int i = 0; i < 8; i++)
#pragma unroll
      for (int j = 0; j < 4; j++)
#pragma unroll
        for (int r = 0; r < 4; r++) acc[i][j][r] += bj[j];
    float mx[32];
#pragma unroll
    for (int i = 0; i < 8; i++)
#pragma unroll
      for (int r = 0; r < 4; r++) {
        float mv = acc[i][0][r];
#pragma unroll
        for (int j = 1; j < 4; j++) mv = fmaxf(mv, acc[i][j][r]);
        mx[i * 4 + r] = mv;
      }
#pragma unroll
    for (int t = 0; t < 32; t++) ex[self + t] = mx[t];
    __syncthreads();
#pragma unroll
    for (int t = 0; t < 32; t++) mx[t] = fmaxf(mx[t], ex[part + t]);
    __syncthreads();
    float sm[32];
#pragma unroll
    for (int t = 0; t < 32; t++) sm[t] = 0.f;
#pragma unroll
    for (int i = 0; i < 8; i++)
#pragma unroll
      for (int j = 0; j < 4; j++)
#pragma unroll
        for (int r = 0; r < 4; r++) {
          float p = __expf(acc[i][j][r] - mx[i * 4 + r]);
          acc[i][j][r] = p;
          sm[i * 4 + r] += p;
        }
#pragma unroll
    for (int t = 0; t < 32; t++) ex[self + t] = sm[t];
    __syncthreads();
#pragma unroll
    for (int t = 0; t < 32; t++) sm[t] = 1.f / (sm[t] + ex[part + t]);
#pragma unroll
    for (int i = 0; i < 8; i++)
#pragma unroll
      for (int j = 0; j < 4; j++)
#pragma unroll
        for (int r = 0; r < 4; r++) acc[i][j][r] *= sm[i * 4 + r];
    __syncthreads();
  }

  // ---- epilogue ----
  const int b = m0 >> 11, s0 = m0 & 2047;
  u16* Cs = smem;
  if constexpr (MODE == 0) {
    // qsP: identity cols (perm == n); two 128-row halves, Cs[128][264]
    // 128 rows x 32 chunks = 4096 chunks -> 8 iters x 512 thr
#pragma unroll
    for (int mh = 0; mh < 2; mh++) {
      if ((wm >> 7) == mh) {
#pragma unroll
        for (int j = 0; j < 4; j++) {
          const int c = wn + j * 16 + fr;
#pragma unroll
          for (int i = 0; i < 8; i++) {
            const int rl = i * 16 + ((lane >> 4) << 2);
#pragma unroll
            for (int r = 0; r < 4; r++) Cs[(rl + r) * 264 + c] = f2bf(acc[i][j][r]);
          }
        }
      }
      __syncthreads();
#pragma unroll
      for (int it = 0; it < 8; it++) {
        const int idx = it * 512 + tid;
        const int row = idx >> 5, ch = idx & 31;
        const long base = (long)b * 8388608 + (long)(s0 + mh * 128 + row) * 4096 +
                          bx * 256 + ch * 8;
        *(uint4*)&out[base] = *(const uint4*)&Cs[row * 264 + ch * 8];
      }
      __syncthreads();
    }
  } else {
    // [b,h,e,s] via 4 slabs of 64 tile-cols: Cs[64][264] (s_local 0..255)
    // 64 rows x 32 chunks = 2048 chunks -> 4 iters x 512 thr
#pragma unroll
    for (int sl = 0; sl < 4; sl++) {
      if ((wave & 3) == sl) {
#pragma unroll
        for (int j = 0; j < 4; j++) {
          const float bb = SM ? 0.f : bias[(hbase + j) * 512 + e_];
#pragma unroll
          for (int i = 0; i < 8; i++) {
            us4 w;
#pragma unroll
            for (int r = 0; r < 4; r++) w.v[r] = f2bf(acc[i][j][r] + bb);
            *(us4*)&Cs[(j * 16 + fr) * 264 + wm + i * 16 + ((lane >> 4) << 2)] = w;
          }
        }
      }
      __syncthreads();
#pragma unroll
      for (int it = 0; it < 4; it++) {
        const int idx = it * 512 + tid;
        const int row = idx >> 5, ch = idx & 31;
        const int h = (sl & 1) * 4 + (row >> 4);
        const int e = bx * 32 + (sl >> 1) * 16 + (row & 15);
        const long base = (long)(b * 8 + h) * 1048576 + (long)e * 2048 + s0 + ch * 8;
        *(uint4*)&out[base] = *(const uint4*)&Cs[row * 264 + ch * 8];
      }
      __syncthreads();
    }
  }
#undef RD_P0
#undef RD_P1
#undef MMBLK
}

// ================= r9 128x128 core for ctx / W2 / final =================
#define M_PLAIN 2
#define M_W2    3
#define M_FINAL 4
#define M_CTXS  5

template<int MODE>
__global__ __launch_bounds__(256, 2)
void gemm_kernel(const u16* __restrict__ A, long sAz, int lda,
                 const u16* __restrict__ B, long sBz, int ldb,
                 void* __restrict__ Cv, long sCz, int ldc,
                 int nx, int ny, int K)
{
  __shared__ __align__(16) u16 smem[24576];

  const int nwg = gridDim.x;
  const int chunk = nwg >> 3;
  const int bid = blockIdx.x;
  const int wg = (bid & 7) * chunk + (bid >> 3);
  const int nxy = nx * ny;
  const int z = wg / nxy;
  const int rem = wg - z * nxy;
  const int by = rem / nx;
  const int bx = rem - by * nx;

  const int tid = threadIdx.x;
  const int lane = tid & 63;
  const int wave = tid >> 6;
  const int wm = (wave >> 1) * 64;
  const int wn = (wave & 1) * 64;
  const int m0 = by * 128;
  const int n0 = bx * 128;

  const u16* Az; const u16* Bz;
  if constexpr (MODE == M_CTXS) {
    const int bh = z & 31, kc = z >> 5;
    Az = A + (long)bh * 1048576 + kc * 1024;
    Bz = B + (long)bh * 1048576 + kc * 1024;
  } else if constexpr (MODE == M_W2) {
    Az = A + (long)z * 262144;
    Bz = B + (long)(z & 7) * 262144;
  } else if constexpr (MODE == M_FINAL) {
    Az = A + (long)(z >> 2) * 8388608 + (z & 3) * 1024;
    Bz = B + (long)(z >> 2) * 2097152 + (z & 3) * 1024;
  } else {
    Az = A + (long)z * sAz;
    Bz = B + (long)z * sBz;
  }

  const int srow = tid >> 2;
  const int scol = (((tid & 3) ^ ((tid >> 3) & 3)) << 3);
  const u16* aptr0 = Az + (long)(m0 + srow) * lda + scol;
  const u16* aptr1 = aptr0 + (long)64 * lda;
  const u16* bptr0 = Bz + (long)(n0 + srow) * ldb + scol;
  const u16* bptr1 = bptr0 + (long)64 * ldb;

  f32x4_t acc[4][4];
#pragma unroll
  for (int i = 0; i < 4; i++)
#pragma unroll
    for (int j = 0; j < 4; j++) acc[i][j] = (f32x4_t){0.f, 0.f, 0.f, 0.f};

  const int kg = lane >> 4;
  const int fr = lane & 15;
  const int nt = K >> 5;

  int aoffL[4], boffL[4];
#pragma unroll
  for (int i = 0; i < 4; i++) {
    const int r = wm + i * 16 + fr;
    aoffL[i] = r * 32 + ((kg ^ ((r >> 1) & 3)) << 3);
  }
#pragma unroll
  for (int j = 0; j < 4; j++) {
    const int r = wn + j * 16 + fr;
    boffL[j] = 4096 + r * 32 + ((kg ^ ((r >> 1) & 3)) << 3);
  }

  auto stage = [&](int t, u16* nb) {
    const int ko = t * 32;
    gload16(aptr0 + ko, nb + tid * 8);
    gload16(aptr1 + ko, nb + (tid + 256) * 8);
    gload16(bptr0 + ko, nb + 4096 + tid * 8);
    gload16(bptr1 + ko, nb + 4096 + (tid + 256) * 8);
  };

  stage(0, smem);
  stage(1, smem + 8192);

  for (int t = 0; t < nt; t++) {
    if (t < nt - 1) VMC(4);
    else            VMC(0);
    BAR();
    asm volatile("" ::: "memory");
    if (t + 2 < nt) stage(t + 2, smem + ((t + 2) % 3) * 8192);
    const u16* cb = smem + (t % 3) * 8192;
    bf16x8_t afr[4], bfr[4];
#pragma unroll
    for (int i = 0; i < 4; i++) afr[i] = *(const bf16x8_t*)&cb[aoffL[i]];
#pragma unroll
    for (int j = 0; j < 4; j++) bfr[j] = *(const bf16x8_t*)&cb[boffL[j]];
#pragma unroll
    for (int i = 0; i < 4; i++)
#pragma unroll
      for (int j = 0; j < 4; j++)
        acc[i][j] = __builtin_amdgcn_mfma_f32_16x16x32_bf16(afr[i], bfr[j], acc[i][j], 0, 0, 0);
  }
  __syncthreads();

  if constexpr (MODE == M_FINAL || MODE == M_CTXS) {
    float* o;
    if constexpr (MODE == M_FINAL)
      o = (float*)Cv + (long)(z & 3) * 4194304 + (long)(z >> 2) * 1048576;
    else
      o = (float*)Cv + (long)z * 262144;
#pragma unroll
    for (int i = 0; i < 4; i++) {
      const int rbase = m0 + wm + i * 16 + ((lane >> 4) << 2);
#pragma unroll
      for (int j = 0; j < 4; j++) {
        const int gc = n0 + wn + j * 16 + fr;
#pragma unroll
        for (int r = 0; r < 4; r++)
          o[(long)(rbase + r) * ldc + gc] = acc[i][j][r];
      }
    }
    return;
  }

  constexpr int CW = 136;
  u16* Cs = smem;
  if constexpr (MODE == M_W2) {
#pragma unroll
    for (int j = 0; j < 4; j++) {
      const int c = wn + j * 16 + fr;
#pragma unroll
      for (int i = 0; i < 4; i++) {
        us4 w;
#pragma unroll
        for (int r = 0; r < 4; r++) w.v[r] = f2bf(acc[i][j][r]);
        *(us4*)&Cs[c * CW + wm + i * 16 + ((lane >> 4) << 2)] = w;
      }
    }
  } else {
#pragma unroll
    for (int j = 0; j < 4; j++) {
      const int c = wn + j * 16 + fr;
#pragma unroll
      for (int i = 0; i < 4; i++) {
        const int rbase = wm + i * 16 + ((lane >> 4) << 2);
#pragma unroll
        for (int r = 0; r < 4; r++)
          Cs[(rbase + r) * CW + c] = f2bf(acc[i][j][r]);
      }
    }
  }
  __syncthreads();

  u16* dst = (u16*)Cv;
  if constexpr (MODE == M_W2) {
    const int b = z >> 3, h = z & 7;
    const long base0 = (long)b * 2097152 + (long)n0 * 4096 + ((m0 >> 4) << 7) + h * 16;
#pragma unroll
    for (int it = 0; it < 4; it++) {
      const int idx = it * 256 + tid;
      const int row = idx >> 3, ch = idx & 7;
      const long base = base0 + (long)row * 4096 + ch * 128;
      *(uint4*)&dst[base] = *(const uint4*)&Cs[row * CW + ch * 16];
      *(uint4*)&dst[base + 8] = *(const uint4*)&Cs[row * CW + ch * 16 + 8];
    }
  } else {  // M_PLAIN
    const long base = (long)z * sCz + (long)m0 * ldc + n0;
#pragma unroll
    for (int it = 0; it < 8; it++) {
      const int idx = it * 256 + tid;
      const int row = idx >> 4, ch = idx & 15;
      *(uint4*)&dst[base + (long)row * ldc + ch * 8] = *(const uint4*)&Cs[row * CW + ch * 8];
    }
  }
}

// ---------------- support kernels ----------------
__global__ void cvt3_kernel(const float* __restrict__ q, const float* __restrict__ k,
                            const float* __restrict__ v, u16* __restrict__ qb,
                            u16* __restrict__ kb, u16* __restrict__ vb) {
  const int arr = blockIdx.x >> 11;
  const int lb = blockIdx.x & 2047;
  const float* in = arr == 0 ? q : (arr == 1 ? k : v);
  u16* out = arr == 0 ? qb : (arr == 1 ? kb : vb);
  const long i = ((long)lb * 256 + threadIdx.x) * 8;
  float4 a = *(const float4*)(in + i);
  float4 b = *(const float4*)(in + i + 4);
  u16 t[8] = {f2bf(a.x), f2bf(a.y), f2bf(a.z), f2bf(a.w),
              f2bf(b.x), f2bf(b.y), f2bf(b.z), f2bf(b.w)};
  uint4 w; __builtin_memcpy(&w, t, 16);
  *(uint4*)(out + i) = w;
}

// WT[(e>>4)*128 + h*16 + (e&15)][d] = bf16(W[h][d][e])
__global__ void tcvt3_kernel(const float* __restrict__ Wq, const float* __restrict__ Wk,
                             const float* __restrict__ Wv, u16* __restrict__ WqT,
                             u16* __restrict__ WkT, u16* __restrict__ WvT)
{
  __shared__ float tile[32][33];
  const int arr = blockIdx.z >> 3;
  const int h = blockIdx.z & 7;
  const float* in = (arr == 0 ? Wq : (arr == 1 ? Wk : Wv)) + (long)h * 262144;
  u16* out = arr == 0 ? WqT : (arr == 1 ? WkT : WvT);
  const int c0 = blockIdx.x * 32, r0 = blockIdx.y * 32;
#pragma unroll
  for (int yy = threadIdx.y; yy < 32; yy += 8)
    tile[yy][threadIdx.x] = in[(long)(r0 + yy) * 512 + c0 + threadIdx.x];
  __syncthreads();
#pragma unroll
  for (int yy = threadIdx.y; yy < 32; yy += 8) {
    const int e = c0 + yy;
    const int rowp = ((e >> 4) << 7) + h * 16 + (e & 15);
    out[(long)rowp * 512 + r0 + threadIdx.x] = f2bf(tile[threadIdx.x][yy]);
  }
}

// WoT2[h][f][e] = bf16(Wo[e*8+h][f])
__global__ void tcvt_wo2(const float* __restrict__ in, u16* __restrict__ out) {
  __shared__ float tile[32][33];
  const int h = blockIdx.z;
  const int e0 = blockIdx.x * 32, f0 = blockIdx.y * 32;
#pragma unroll
  for (int yy = threadIdx.y; yy < 32; yy += 8)
    tile[yy][threadIdx.x] = in[(long)((e0 + yy) * 8 + h) * 512 + f0 + threadIdx.x];
  __syncthreads();
#pragma unroll
  for (int yy = threadIdx.y; yy < 32; yy += 8)
    out[(long)h * 262144 + (long)(f0 + yy) * 512 + e0 + threadIdx.x] =
        f2bf(tile[threadIdx.x][yy]);
}

__global__ void reduce4_kernel(const float* __restrict__ p, const float* __restrict__ bo,
                               float* __restrict__ out)
{
  const long S = 8192L * 512;
  const long i4 = ((long)blockIdx.x * 256 + threadIdx.x) * 4;
  float4 a = *(const float4*)(p + i4);
  float4 b = *(const float4*)(p + S + i4);
  float4 c = *(const float4*)(p + 2 * S + i4);
  float4 d = *(const float4*)(p + 3 * S + i4);
  float4 bb = *(const float4*)(bo + (i4 & 511));
  float4 r;
  r.x = a.x + b.x + c.x + d.x + bb.x;
  r.y = a.y + b.y + c.y + d.y + bb.y;
  r.z = a.z + b.z + c.z + d.z + bb.z;
  r.w = a.w + b.w + c.w + d.w + bb.w;
  *(float4*)(out + i4) = r;
}

__global__ void reduce2c_kernel(const float* __restrict__ p, u16* __restrict__ out)
{
  const long S = 32L * 262144;
  const long i = ((long)blockIdx.x * 256 + threadIdx.x) * 8;
  float4 a0 = *(const float4*)(p + i);
  float4 a1 = *(const float4*)(p + i + 4);
  float4 b0 = *(const float4*)(p + S + i);
  float4 b1 = *(const float4*)(p + S + i + 4);
  u16 t[8] = {f2bf(a0.x + b0.x), f2bf(a0.y + b0.y), f2bf(a0.z + b0.z), f2bf(a0.w + b0.w),
              f2bf(a1.x + b1.x), f2bf(a1.y + b1.y), f2bf(a1.z + b1.z), f2bf(a1.w + b1.w)};
  uint4 w; __builtin_memcpy(&w, t, 16);
  *(uint4*)(out + i) = w;
}

extern "C" void kernel_launch(void* const* d_in, const int* in_sizes, int n_in,
                              void* d_out, int out_size, void* d_ws, size_t ws_size,
                              hipStream_t stream) {
  const float* q  = (const float*)d_in[0];
  const float* k  = (const float*)d_in[1];
  const float* v  = (const float*)d_in[2];
  const float* Wq = (const float*)d_in[3];
  const float* bq = (const float*)d_in[4];
  const float* Wk = (const float*)d_in[5];
  const float* bk = (const float*)d_in[6];
  const float* Wv = (const float*)d_in[7];
  const float* bv = (const float*)d_in[8];
  const float* Wo = (const float*)d_in[9];
  const float* bo = (const float*)d_in[10];
  float* outp = (float*)d_out;

  char* ws = (char*)d_ws;
  u16* qs    = (u16*)(ws);                  //   0- 64 qsP; live to final
  u16* WqT   = (u16*)(ws + (64L  << 20));   //  64- 68  dead before ksT
  u16* qb    = (u16*)(ws + (72L  << 20));   //  72- 80  dead before ksT
  u16* ksT   = (u16*)(ws + (64L  << 20));   //  64-128 [b,h,e,s]
  u16* W2Pt  = (u16*)(ws + (64L  << 20));   //  64- 80 after ctx
  u16* kb    = (u16*)(ws + (128L << 20));   // 128-136  dead before vsT
  u16* vsT   = (u16*)(ws + (128L << 20));   // 128-192 [b,h,e,s]
  float* Pf  = (float*)(ws + (128L << 20)); // 128-192 final partials
  u16* vb    = (u16*)(ws + (192L << 20));   // 192-200  dead before ctx
  u16* WkT   = (u16*)(ws + (200L << 20));   // 200-204
  u16* WvT   = (u16*)(ws + (204L << 20));   // 204-208
  u16* ctxT  = (u16*)(ws + (192L << 20));   // 192-208 ctx [b,h][d][e]
  u16* WoT2  = (u16*)(ws + (208L << 20));   // 208-212 [h][f][e]
  float* Pfc = (float*)(ws + (212L << 20)); // 212-276 ctx partials (guarded)
  const bool ctx_split = ws_size >= (286L << 20);

  cvt3_kernel<<<6144, 256, 0, stream>>>(q, k, v, qb, kb, vb);

  dim3 tb(32, 8, 1);
  tcvt3_kernel<<<dim3(16, 16, 24), tb, 0, stream>>>(Wq, Wk, Wv, WqT, WkT, WvT);
  tcvt_wo2<<<dim3(16, 16, 8), tb, 0, stream>>>(Wo, WoT2);

  // projections: 8-phase 256x256 core, grid 512 (16 bx * 32 by)
  proj8_kernel<0, true><<<512, 512, 0, stream>>>(qb, WqT, bq, qs);
  proj8_kernel<1, true><<<512, 512, 0, stream>>>(kb, WkT, bk, ksT);
  proj8_kernel<1, false><<<512, 512, 0, stream>>>(vb, WvT, bv, vsT);

  // ctx[b,h][d][e] = sum_s ksT[d][s]*vsT[e][s]
  if (ctx_split) {
    gemm_kernel<M_CTXS><<<1024, 256, 0, stream>>>(
        ksT, 0, 2048, vsT, 0, 2048, Pfc, 0, 512, 4, 4, 1024);
    reduce2c_kernel<<<4096, 256, 0, stream>>>(Pfc, ctxT);
  } else {
    gemm_kernel<M_PLAIN><<<512, 256, 0, stream>>>(
        ksT, 1048576, 2048, vsT, 1048576, 2048, ctxT, 262144, 512, 4, 4, 2048);
  }

  // W2Pt[b][f][perm(h,d)] = sum_e ctx[b,h][d][e]*WoT2[h][f][e]
  gemm_kernel<M_W2><<<512, 256, 0, stream>>>(
      ctxT, 262144, 512, WoT2, 0, 512, W2Pt, 0, 0, 4, 4, 512);

  // final partials: K=4096 split 4x1024
  gemm_kernel<M_FINAL><<<1024, 256, 0, stream>>>(
      qs, 0, 4096, W2Pt, 0, 4096, Pf, 0, 512, 4, 16, 1024);

  reduce4_kernel<<<4096, 256, 0, stream>>>(Pf, bo, outp);
}

// Round 13
// 290.183 us; speedup vs baseline: 1.1626x; 1.1626x over previous
//
#include <hip/hip_runtime.h>
#include <hip/hip_bf16.h>

typedef unsigned short u16;
typedef __bf16 bf16x8_t __attribute__((ext_vector_type(8)));
typedef float f32x4_t __attribute__((ext_vector_type(4)));

struct alignas(8) us4 { u16 v[4]; };

__device__ __forceinline__ u16 f2bf(float f) {
  __hip_bfloat16 h = __float2bfloat16(f);
  u16 u; __builtin_memcpy(&u, &h, 2); return u;
}

__device__ __forceinline__ void gload16(const u16* g, u16* l) {
  __builtin_amdgcn_global_load_lds(
      (const __attribute__((address_space(1))) void*)g,
      (__attribute__((address_space(3))) void*)l, 16, 0, 0);
}

#define BAR()  __builtin_amdgcn_s_barrier()
#define VMC(n) asm volatile("s_waitcnt vmcnt(%0)" :: "i"(n) : "memory")

// ============ projection kernel (zsel picks q/k/v) ============
// launch A: grid 4096, zoff 0 -> zsel {0,1} (Q,K).  launch B: grid 2048,
// zoff 2 -> zsel 2 (V).  128x128 tile, BK=32, 3-buf depth-2 counted-vmcnt
// loop (r9-proven), chunk-XOR swizzled LDS both-sides. Weights pre-interleaved
// (col n -> h=(n>>4)&7, e=(n>>7)*16+(n&15)).
// zsel 0: softmax + qsP[b][s][n] (identity cols). zsel 1: softmax + [b,h,e,s].
// zsel 2: bias only + [b,h,e,s].
// ALIASING CONTRACT (launch-order dependent): launch A reads qb/kb/W{q,k}T at
// 128-152 MiB and writes 0-128; launch B writes vsT 128-192 (A's inputs dead).
__global__ __launch_bounds__(256, 2)
void proj3_kernel(const u16* __restrict__ qb, const u16* __restrict__ kb,
                  const u16* __restrict__ vb, const u16* __restrict__ WqT,
                  const u16* __restrict__ WkT, const u16* __restrict__ WvT,
                  const float* __restrict__ bq, const float* __restrict__ bk,
                  const float* __restrict__ bv, u16* __restrict__ qs,
                  u16* __restrict__ ksT, u16* __restrict__ vsT, int zoff)
{
  __shared__ __align__(16) u16 smem[24576];

  const int bid = blockIdx.x;
  const int chunk = gridDim.x >> 3;
  const int wg = (bid & 7) * chunk + (bid >> 3);   // XCD-bijective (grid % 8 == 0)
  const int zsel = zoff + (wg >> 11);
  const int rem = wg & 2047;
  const int by = rem >> 5;
  const int bx = rem & 31;

  const int tid = threadIdx.x;
  const int lane = tid & 63;
  const int wave = tid >> 6;
  const int wm = (wave >> 1) * 64;
  const int wn = (wave & 1) * 64;
  const int m0 = by * 128;

  const u16* Az = zsel == 0 ? qb : (zsel == 1 ? kb : vb);
  const u16* Bz = zsel == 0 ? WqT : (zsel == 1 ? WkT : WvT);
  const float* bias = zsel == 0 ? bq : (zsel == 1 ? bk : bv);
  u16* outp = zsel == 0 ? qs : (zsel == 1 ? ksT : vsT);
  const bool doSM = (zsel < 2);

  const int srow = tid >> 2;
  const int scol = (((tid & 3) ^ ((tid >> 3) & 3)) << 3);
  const u16* aptr0 = Az + (long)(m0 + srow) * 512 + scol;
  const u16* aptr1 = aptr0 + (long)64 * 512;
  const u16* bptr0 = Bz + (long)(bx * 128 + srow) * 512 + scol;
  const u16* bptr1 = bptr0 + (long)64 * 512;

  f32x4_t acc[4][4];
#pragma unroll
  for (int i = 0; i < 4; i++)
#pragma unroll
    for (int j = 0; j < 4; j++) acc[i][j] = (f32x4_t){0.f, 0.f, 0.f, 0.f};

  const int kg = lane >> 4;
  const int fr = lane & 15;

  int aoffL[4], boffL[4];
#pragma unroll
  for (int i = 0; i < 4; i++) {
    const int r = wm + i * 16 + fr;
    aoffL[i] = r * 32 + ((kg ^ ((r >> 1) & 3)) << 3);
  }
#pragma unroll
  for (int j = 0; j < 4; j++) {
    const int r = wn + j * 16 + fr;
    boffL[j] = 4096 + r * 32 + ((kg ^ ((r >> 1) & 3)) << 3);
  }

  auto stage = [&](int t, u16* nb) {
    const int ko = t * 32;
    gload16(aptr0 + ko, nb + tid * 8);
    gload16(aptr1 + ko, nb + (tid + 256) * 8);
    gload16(bptr0 + ko, nb + 4096 + tid * 8);
    gload16(bptr1 + ko, nb + 4096 + (tid + 256) * 8);
  };

  stage(0, smem);
  stage(1, smem + 8192);

  for (int t = 0; t < 16; t++) {
    if (t < 15) VMC(4);
    else        VMC(0);
    BAR();
    asm volatile("" ::: "memory");
    if (t + 2 < 16) stage(t + 2, smem + ((t + 2) % 3) * 8192);
    const u16* cb = smem + (t % 3) * 8192;
    bf16x8_t afr[4], bfr[4];
#pragma unroll
    for (int i = 0; i < 4; i++) afr[i] = *(const bf16x8_t*)&cb[aoffL[i]];
#pragma unroll
    for (int j = 0; j < 4; j++) bfr[j] = *(const bf16x8_t*)&cb[boffL[j]];
#pragma unroll
    for (int i = 0; i < 4; i++)
#pragma unroll
      for (int j = 0; j < 4; j++)
        acc[i][j] = __builtin_amdgcn_mfma_f32_16x16x32_bf16(afr[i], bfr[j], acc[i][j], 0, 0, 0);
  }
  __syncthreads();  // full drain before smem reuse

  // ---- fused softmax over heads (zsel 0,1) ----
  if (doSM) {
    float* ex = (float*)smem;          // stride 17 -> conflict-free
    float* ex2 = ex + 4352;
    const int wmg = wave >> 1, wng = wave & 1;
    const int self = ((wmg * 2 + wng) * 64 + lane) * 17;
    const int part = ((wmg * 2 + (wng ^ 1)) * 64 + lane) * 17;
    float bj[4];
#pragma unroll
    for (int j = 0; j < 4; j++) bj[j] = bias[((wn >> 4) + j) * 512 + bx * 16 + fr];
#pragma unroll
    for (int i = 0; i < 4; i++)
#pragma unroll
      for (int j = 0; j < 4; j++)
#pragma unroll
        for (int r = 0; r < 4; r++) acc[i][j][r] += bj[j];
    float mx[16];
#pragma unroll
    for (int i = 0; i < 4; i++)
#pragma unroll
      for (int r = 0; r < 4; r++) {
        float m = acc[i][0][r];
#pragma unroll
        for (int j = 1; j < 4; j++) m = fmaxf(m, acc[i][j][r]);
        mx[i * 4 + r] = m;
      }
#pragma unroll
    for (int t = 0; t < 16; t++) ex[self + t] = mx[t];
    __syncthreads();
#pragma unroll
    for (int t = 0; t < 16; t++) mx[t] = fmaxf(mx[t], ex[part + t]);
    float sm[16];
#pragma unroll
    for (int t = 0; t < 16; t++) sm[t] = 0.f;
#pragma unroll
    for (int i = 0; i < 4; i++)
#pragma unroll
      for (int j = 0; j < 4; j++)
#pragma unroll
        for (int r = 0; r < 4; r++) {
          float p = __expf(acc[i][j][r] - mx[i * 4 + r]);
          acc[i][j][r] = p;
          sm[i * 4 + r] += p;
        }
#pragma unroll
    for (int t = 0; t < 16; t++) ex2[self + t] = sm[t];
    __syncthreads();
#pragma unroll
    for (int t = 0; t < 16; t++) sm[t] = 1.f / (sm[t] + ex2[part + t]);
#pragma unroll
    for (int i = 0; i < 4; i++)
#pragma unroll
      for (int j = 0; j < 4; j++)
#pragma unroll
        for (int r = 0; r < 4; r++) acc[i][j][r] *= sm[i * 4 + r];
    __syncthreads();
  }

  // ---- LDS-staged epilogue: Cs[128][136] ----
  constexpr int CW = 136;
  u16* Cs = smem;
  const int b = m0 >> 11, s0 = m0 & 2047;
  if (zsel == 0) {
    // qsP[b][s][bx*128 + c]
#pragma unroll
    for (int j = 0; j < 4; j++) {
      const int c = wn + j * 16 + fr;
#pragma unroll
      for (int i = 0; i < 4; i++) {
        const int rbase = wm + i * 16 + ((lane >> 4) << 2);
#pragma unroll
        for (int r = 0; r < 4; r++)
          Cs[(rbase + r) * CW + c] = f2bf(acc[i][j][r]);
      }
    }
    __syncthreads();
    const long base = (long)b * 8388608 + (long)s0 * 4096 + bx * 128;
#pragma unroll
    for (int it = 0; it < 8; it++) {
      const int idx = it * 256 + tid;
      const int row = idx >> 4, ch = idx & 15;
      *(uint4*)&outp[base + (long)row * 4096 + ch * 8] = *(const uint4*)&Cs[row * CW + ch * 8];
    }
  } else {
    // transposed tile: Cs[row = tile col c][col = s]; bias only for v (zsel 2)
#pragma unroll
    for (int j = 0; j < 4; j++) {
      const int c = wn + j * 16 + fr;
      const float bb = doSM ? 0.f : bias[((wn >> 4) + j) * 512 + bx * 16 + fr];
#pragma unroll
      for (int i = 0; i < 4; i++) {
        us4 w;
#pragma unroll
        for (int r = 0; r < 4; r++) w.v[r] = f2bf(acc[i][j][r] + bb);
        *(us4*)&Cs[c * CW + wm + i * 16 + ((lane >> 4) << 2)] = w;
      }
    }
    __syncthreads();
#pragma unroll
    for (int it = 0; it < 8; it++) {
      const int idx = it * 256 + tid;
      const int row = idx >> 4, ch = idx & 15;
      const long base = (long)(b * 8 + (row >> 4)) * 1048576 +
                        (long)(bx * 16 + (row & 15)) * 2048 + s0;
      *(uint4*)&outp[base + ch * 8] = *(const uint4*)&Cs[row * CW + ch * 8];
    }
  }
}

// ================= r9 128x128 core for ctx / W2 / final =================
#define M_PLAIN 2
#define M_W2    3
#define M_FINAL 4
#define M_CTXS  5

template<int MODE>
__global__ __launch_bounds__(256, 2)
void gemm_kernel(const u16* __restrict__ A, long sAz, int lda,
                 const u16* __restrict__ B, long sBz, int ldb,
                 void* __restrict__ Cv, long sCz, int ldc,
                 int nx, int ny, int K)
{
  __shared__ __align__(16) u16 smem[24576];

  const int nwg = gridDim.x;
  const int chunk = nwg >> 3;
  const int bid = blockIdx.x;
  const int wg = (bid & 7) * chunk + (bid >> 3);
  const int nxy = nx * ny;
  const int z = wg / nxy;
  const int rem = wg - z * nxy;
  const int by = rem / nx;
  const int bx = rem - by * nx;

  const int tid = threadIdx.x;
  const int lane = tid & 63;
  const int wave = tid >> 6;
  const int wm = (wave >> 1) * 64;
  const int wn = (wave & 1) * 64;
  const int m0 = by * 128;
  const int n0 = bx * 128;

  const u16* Az; const u16* Bz;
  if constexpr (MODE == M_CTXS) {
    const int bh = z & 31, kc = z >> 5;
    Az = A + (long)bh * 1048576 + kc * 1024;
    Bz = B + (long)bh * 1048576 + kc * 1024;
  } else if constexpr (MODE == M_W2) {
    Az = A + (long)z * 262144;
    Bz = B + (long)(z & 7) * 262144;
  } else if constexpr (MODE == M_FINAL) {
    Az = A + (long)(z >> 2) * 8388608 + (z & 3) * 1024;
    Bz = B + (long)(z >> 2) * 2097152 + (z & 3) * 1024;
  } else {
    Az = A + (long)z * sAz;
    Bz = B + (long)z * sBz;
  }

  const int srow = tid >> 2;
  const int scol = (((tid & 3) ^ ((tid >> 3) & 3)) << 3);
  const u16* aptr0 = Az + (long)(m0 + srow) * lda + scol;
  const u16* aptr1 = aptr0 + (long)64 * lda;
  const u16* bptr0 = Bz + (long)(n0 + srow) * ldb + scol;
  const u16* bptr1 = bptr0 + (long)64 * ldb;

  f32x4_t acc[4][4];
#pragma unroll
  for (int i = 0; i < 4; i++)
#pragma unroll
    for (int j = 0; j < 4; j++) acc[i][j] = (f32x4_t){0.f, 0.f, 0.f, 0.f};

  const int kg = lane >> 4;
  const int fr = lane & 15;
  const int nt = K >> 5;

  int aoffL[4], boffL[4];
#pragma unroll
  for (int i = 0; i < 4; i++) {
    const int r = wm + i * 16 + fr;
    aoffL[i] = r * 32 + ((kg ^ ((r >> 1) & 3)) << 3);
  }
#pragma unroll
  for (int j = 0; j < 4; j++) {
    const int r = wn + j * 16 + fr;
    boffL[j] = 4096 + r * 32 + ((kg ^ ((r >> 1) & 3)) << 3);
  }

  auto stage = [&](int t, u16* nb) {
    const int ko = t * 32;
    gload16(aptr0 + ko, nb + tid * 8);
    gload16(aptr1 + ko, nb + (tid + 256) * 8);
    gload16(bptr0 + ko, nb + 4096 + tid * 8);
    gload16(bptr1 + ko, nb + 4096 + (tid + 256) * 8);
  };

  stage(0, smem);
  stage(1, smem + 8192);

  for (int t = 0; t < nt; t++) {
    if (t < nt - 1) VMC(4);
    else            VMC(0);
    BAR();
    asm volatile("" ::: "memory");
    if (t + 2 < nt) stage(t + 2, smem + ((t + 2) % 3) * 8192);
    const u16* cb = smem + (t % 3) * 8192;
    bf16x8_t afr[4], bfr[4];
#pragma unroll
    for (int i = 0; i < 4; i++) afr[i] = *(const bf16x8_t*)&cb[aoffL[i]];
#pragma unroll
    for (int j = 0; j < 4; j++) bfr[j] = *(const bf16x8_t*)&cb[boffL[j]];
#pragma unroll
    for (int i = 0; i < 4; i++)
#pragma unroll
      for (int j = 0; j < 4; j++)
        acc[i][j] = __builtin_amdgcn_mfma_f32_16x16x32_bf16(afr[i], bfr[j], acc[i][j], 0, 0, 0);
  }
  __syncthreads();

  if constexpr (MODE == M_FINAL || MODE == M_CTXS) {
    float* o;
    if constexpr (MODE == M_FINAL)
      o = (float*)Cv + (long)(z & 3) * 4194304 + (long)(z >> 2) * 1048576;
    else
      o = (float*)Cv + (long)z * 262144;
#pragma unroll
    for (int i = 0; i < 4; i++) {
      const int rbase = m0 + wm + i * 16 + ((lane >> 4) << 2);
#pragma unroll
      for (int j = 0; j < 4; j++) {
        const int gc = n0 + wn + j * 16 + fr;
#pragma unroll
        for (int r = 0; r < 4; r++)
          o[(long)(rbase + r) * ldc + gc] = acc[i][j][r];
      }
    }
    return;
  }

  constexpr int CW = 136;
  u16* Cs = smem;
  if constexpr (MODE == M_W2) {
#pragma unroll
    for (int j = 0; j < 4; j++) {
      const int c = wn + j * 16 + fr;
#pragma unroll
      for (int i = 0; i < 4; i++) {
        us4 w;
#pragma unroll
        for (int r = 0; r < 4; r++) w.v[r] = f2bf(acc[i][j][r]);
        *(us4*)&Cs[c * CW + wm + i * 16 + ((lane >> 4) << 2)] = w;
      }
    }
  } else {
#pragma unroll
    for (int j = 0; j < 4; j++) {
      const int c = wn + j * 16 + fr;
#pragma unroll
      for (int i = 0; i < 4; i++) {
        const int rbase = wm + i * 16 + ((lane >> 4) << 2);
#pragma unroll
        for (int r = 0; r < 4; r++)
          Cs[(rbase + r) * CW + c] = f2bf(acc[i][j][r]);
      }
    }
  }
  __syncthreads();

  u16* dst = (u16*)Cv;
  if constexpr (MODE == M_W2) {
    const int b = z >> 3, h = z & 7;
    const long base0 = (long)b * 2097152 + (long)n0 * 4096 + ((m0 >> 4) << 7) + h * 16;
#pragma unroll
    for (int it = 0; it < 4; it++) {
      const int idx = it * 256 + tid;
      const int row = idx >> 3, ch = idx & 7;
      const long base = base0 + (long)row * 4096 + ch * 128;
      *(uint4*)&dst[base] = *(const uint4*)&Cs[row * CW + ch * 16];
      *(uint4*)&dst[base + 8] = *(const uint4*)&Cs[row * CW + ch * 16 + 8];
    }
  } else {  // M_PLAIN
    const long base = (long)z * sCz + (long)m0 * ldc + n0;
#pragma unroll
    for (int it = 0; it < 8; it++) {
      const int idx = it * 256 + tid;
      const int row = idx >> 4, ch = idx & 15;
      *(uint4*)&dst[base + (long)row * ldc + ch * 8] = *(const uint4*)&Cs[row * CW + ch * 8];
    }
  }
}

// ---------------- support kernels ----------------
__global__ void cvt3_kernel(const float* __restrict__ q, const float* __restrict__ k,
                            const float* __restrict__ v, u16* __restrict__ qb,
                            u16* __restrict__ kb, u16* __restrict__ vb) {
  const int arr = blockIdx.x >> 11;
  const int lb = blockIdx.x & 2047;
  const float* in = arr == 0 ? q : (arr == 1 ? k : v);
  u16* out = arr == 0 ? qb : (arr == 1 ? kb : vb);
  const long i = ((long)lb * 256 + threadIdx.x) * 8;
  float4 a = *(const float4*)(in + i);
  float4 b = *(const float4*)(in + i + 4);
  u16 t[8] = {f2bf(a.x), f2bf(a.y), f2bf(a.z), f2bf(a.w),
              f2bf(b.x), f2bf(b.y), f2bf(b.z), f2bf(b.w)};
  uint4 w; __builtin_memcpy(&w, t, 16);
  *(uint4*)(out + i) = w;
}

// WT[(e>>4)*128 + h*16 + (e&15)][d] = bf16(W[h][d][e])
__global__ void tcvt3_kernel(const float* __restrict__ Wq, const float* __restrict__ Wk,
                             const float* __restrict__ Wv, u16* __restrict__ WqT,
                             u16* __restrict__ WkT, u16* __restrict__ WvT)
{
  __shared__ float tile[32][33];
  const int arr = blockIdx.z >> 3;
  const int h = blockIdx.z & 7;
  const float* in = (arr == 0 ? Wq : (arr == 1 ? Wk : Wv)) + (long)h * 262144;
  u16* out = arr == 0 ? WqT : (arr == 1 ? WkT : WvT);
  const int c0 = blockIdx.x * 32, r0 = blockIdx.y * 32;
#pragma unroll
  for (int yy = threadIdx.y; yy < 32; yy += 8)
    tile[yy][threadIdx.x] = in[(long)(r0 + yy) * 512 + c0 + threadIdx.x];
  __syncthreads();
#pragma unroll
  for (int yy = threadIdx.y; yy < 32; yy += 8) {
    const int e = c0 + yy;
    const int rowp = ((e >> 4) << 7) + h * 16 + (e & 15);
    out[(long)rowp * 512 + r0 + threadIdx.x] = f2bf(tile[threadIdx.x][yy]);
  }
}

// WoT2[h][f][e] = bf16(Wo[e*8+h][f])
__global__ void tcvt_wo2(const float* __restrict__ in, u16* __restrict__ out) {
  __shared__ float tile[32][33];
  const int h = blockIdx.z;
  const int e0 = blockIdx.x * 32, f0 = blockIdx.y * 32;
#pragma unroll
  for (int yy = threadIdx.y; yy < 32; yy += 8)
    tile[yy][threadIdx.x] = in[(long)((e0 + yy) * 8 + h) * 512 + f0 + threadIdx.x];
  __syncthreads();
#pragma unroll
  for (int yy = threadIdx.y; yy < 32; yy += 8)
    out[(long)h * 262144 + (long)(f0 + yy) * 512 + e0 + threadIdx.x] =
        f2bf(tile[threadIdx.x][yy]);
}

__global__ void reduce4_kernel(const float* __restrict__ p, const float* __restrict__ bo,
                               float* __restrict__ out)
{
  const long S = 8192L * 512;
  const long i4 = ((long)blockIdx.x * 256 + threadIdx.x) * 4;
  float4 a = *(const float4*)(p + i4);
  float4 b = *(const float4*)(p + S + i4);
  float4 c = *(const float4*)(p + 2 * S + i4);
  float4 d = *(const float4*)(p + 3 * S + i4);
  float4 bb = *(const float4*)(bo + (i4 & 511));
  float4 r;
  r.x = a.x + b.x + c.x + d.x + bb.x;
  r.y = a.y + b.y + c.y + d.y + bb.y;
  r.z = a.z + b.z + c.z + d.z + bb.z;
  r.w = a.w + b.w + c.w + d.w + bb.w;
  *(float4*)(out + i4) = r;
}

__global__ void reduce2c_kernel(const float* __restrict__ p, u16* __restrict__ out)
{
  const long S = 32L * 262144;
  const long i = ((long)blockIdx.x * 256 + threadIdx.x) * 8;
  float4 a0 = *(const float4*)(p + i);
  float4 a1 = *(const float4*)(p + i + 4);
  float4 b0 = *(const float4*)(p + S + i);
  float4 b1 = *(const float4*)(p + S + i + 4);
  u16 t[8] = {f2bf(a0.x + b0.x), f2bf(a0.y + b0.y), f2bf(a0.z + b0.z), f2bf(a0.w + b0.w),
              f2bf(a1.x + b1.x), f2bf(a1.y + b1.y), f2bf(a1.z + b1.z), f2bf(a1.w + b1.w)};
  uint4 w; __builtin_memcpy(&w, t, 16);
  *(uint4*)(out + i) = w;
}

extern "C" void kernel_launch(void* const* d_in, const int* in_sizes, int n_in,
                              void* d_out, int out_size, void* d_ws, size_t ws_size,
                              hipStream_t stream) {
  const float* q  = (const float*)d_in[0];
  const float* k  = (const float*)d_in[1];
  const float* v  = (const float*)d_in[2];
  const float* Wq = (const float*)d_in[3];
  const float* bq = (const float*)d_in[4];
  const float* Wk = (const float*)d_in[5];
  const float* bk = (const float*)d_in[6];
  const float* Wv = (const float*)d_in[7];
  const float* bv = (const float*)d_in[8];
  const float* Wo = (const float*)d_in[9];
  const float* bo = (const float*)d_in[10];
  float* outp = (float*)d_out;

  char* ws = (char*)d_ws;
  // layout re-derived for 2-launch merged projections (peak 212 MiB):
  u16* qs    = (u16*)(ws);                  //   0- 64 qsP; live to final
  u16* ksT   = (u16*)(ws + (64L  << 20));   //  64-128 [b,h,e,s]; dead after ctx
  u16* W2Pt  = (u16*)(ws + (64L  << 20));   //  64- 80 after ctx (ksT dead)
  u16* vsT   = (u16*)(ws + (128L << 20));   // 128-192 [b,h,e,s]; written launch B
  u16* qb    = (u16*)(ws + (128L << 20));   // 128-136 inside vsT; dead after launch A
  u16* kb    = (u16*)(ws + (136L << 20));   // 136-144 inside vsT; dead after launch A
  u16* WqT   = (u16*)(ws + (144L << 20));   // 144-148 inside vsT; dead after launch A
  u16* WkT   = (u16*)(ws + (148L << 20));   // 148-152 inside vsT; dead after launch A
  float* Pf  = (float*)(ws + (128L << 20)); // 128-192 final partials (vsT dead)
  u16* vb    = (u16*)(ws + (192L << 20));   // 192-200; dead after launch B
  u16* WvT   = (u16*)(ws + (200L << 20));   // 200-204; dead after launch B
  u16* ctxT  = (u16*)(ws + (192L << 20));   // 192-208 ctx (vb/WvT dead)
  u16* WoT2  = (u16*)(ws + (208L << 20));   // 208-212 [h][f][e]
  float* Pfc = (float*)(ws + (212L << 20)); // 212-276 ctx partials (guarded)
  const bool ctx_split = ws_size >= (286L << 20);

  cvt3_kernel<<<6144, 256, 0, stream>>>(q, k, v, qb, kb, vb);

  dim3 tb(32, 8, 1);
  tcvt3_kernel<<<dim3(16, 16, 24), tb, 0, stream>>>(Wq, Wk, Wv, WqT, WkT, WvT);
  tcvt_wo2<<<dim3(16, 16, 8), tb, 0, stream>>>(Wo, WoT2);

  // launch A: Q + K merged (zsel 0,1); launch B: V (zsel 2)
  proj3_kernel<<<4096, 256, 0, stream>>>(qb, kb, vb, WqT, WkT, WvT,
                                         bq, bk, bv, qs, ksT, vsT, 0);
  proj3_kernel<<<2048, 256, 0, stream>>>(qb, kb, vb, WqT, WkT, WvT,
                                         bq, bk, bv, qs, ksT, vsT, 2);

  // ctx[b,h][d][e] = sum_s ksT[d][s]*vsT[e][s]
  if (ctx_split) {
    gemm_kernel<M_CTXS><<<1024, 256, 0, stream>>>(
        ksT, 0, 2048, vsT, 0, 2048, Pfc, 0, 512, 4, 4, 1024);
    reduce2c_kernel<<<4096, 256, 0, stream>>>(Pfc, ctxT);
  } else {
    gemm_kernel<M_PLAIN><<<512, 256, 0, stream>>>(
        ksT, 1048576, 2048, vsT, 1048576, 2048, ctxT, 262144, 512, 4, 4, 2048);
  }

  // W2Pt[b][f][perm(h,d)] = sum_e ctx[b,h][d][e]*WoT2[h][f][e]
  gemm_kernel<M_W2><<<512, 256, 0, stream>>>(
      ctxT, 262144, 512, WoT2, 0, 512, W2Pt, 0, 0, 4, 4, 512);

  // final partials: K=4096 split 4x1024
  gemm_kernel<M_FINAL><<<1024, 256, 0, stream>>>(
      qs, 0, 4096, W2Pt, 0, 4096, Pf, 0, 512, 4, 16, 1024);

  reduce4_kernel<<<4096, 256, 0, stream>>>(Pf, bo, outp);
}